// Round 15
// baseline (33599.667 us; speedup 1.0000x reference)
//
#include <hip/hip_runtime.h>
#include <stdint.h>

typedef __bf16 bf16;
typedef __bf16 bf16x8 __attribute__((ext_vector_type(8)));
typedef float f32x4 __attribute__((ext_vector_type(4)));
typedef int   i32x4 __attribute__((ext_vector_type(4)));

// ---------------------------------------------------------------------------
// bf16 split pre-pack (GRU + output weights): f32 [N,K] -> hi/lo bf16 in MFMA
// B-frag layout: pk[half][nf][ks][lane][8], lane=(n&15)|(((k&31)>>3)<<4).
// ---------------------------------------------------------------------------
__global__ void pack_split(const float* __restrict__ src, bf16* __restrict__ dst,
                           int N, int K, int NFtot, int nfBase)
{
    int gid = blockIdx.x * 256 + threadIdx.x;
    if (gid >= N * K) return;
    int n = gid / K, k = gid - n * K;
    int KS = K >> 5;
    float x = src[gid];
    bf16 hb = (bf16)x;                    // RNE
    bf16 lb = (bf16)(x - (float)hb);      // residual (exact in f32)
    int nf = nfBase + (n >> 4);
    int l  = (n & 15) | (((k & 31) >> 3) << 4);
    int ks = k >> 5;
    int e  = k & 7;
    int base = ((nf * KS + ks) << 9) + (l << 3) + e;
    int half = NFtot * KS * 512;
    dst[base] = hb;
    dst[half + base] = lb;
}

// ---------------------------------------------------------------------------
// i8 pre-pack (ODE weights) for v_mfma_i32_16x16x64_i8 B-frags:
// lane = (n&15) | (((k&63)>>4)<<4), e = k&15, ks64 = k>>6.
// Per-output-column scale s[n] = max|W[n,:]|/127.
// ---------------------------------------------------------------------------
__global__ void pack_i8(const float* __restrict__ src, int8_t* __restrict__ dst,
                        float* __restrict__ scale, int N, int K)
{
    int n = blockIdx.x * 64 + threadIdx.x;
    if (n >= N) return;
    const float* row = src + (long)n * K;
    float m = 0.f;
    for (int k = 0; k < K; ++k) m = fmaxf(m, fabsf(row[k]));
    float s = (m > 0.f) ? (m / 127.f) : 1.f;
    scale[n] = s;
    float inv = 1.f / s;
    int KS64 = K >> 6;
    int nf = n >> 4;
    for (int k = 0; k < K; ++k) {
        int q = __float2int_rn(row[k] * inv);
        int l = (n & 15) | (((k & 63) >> 4) << 4);
        dst[((nf * KS64 + (k >> 6)) << 10) + (l << 4) + (k & 15)] = (int8_t)q;
    }
}

#define MFMA(a, b, c)  __builtin_amdgcn_mfma_f32_16x16x32_bf16(a, b, c, 0, 0, 0)
#define MFMA8(a, b, c) __builtin_amdgcn_mfma_i32_16x16x64_i8(a, b, c, 0, 0, 0)

// ---------------------------------------------------------------------------
// ODE streamer, all-i8: acc_int[i] += qA @ qW[nf0+i]^T  (exact int arithmetic).
// K=512 -> 8 iters of K=64. S8: [ks64][lane][16B]; W frag 16B/lane coalesced.
// NFR=4 at the 128-VGPR tier: compiler can hoist all 32 loads per phase.
// ---------------------------------------------------------------------------
template<int NFR>
__device__ __forceinline__ void mm_i8n(const int8_t* __restrict__ pk, int nf0, int lane,
                                       const int8_t* __restrict__ S8, i32x4* acc)
{
#pragma unroll
    for (int i = 0; i < NFR; ++i) { i32x4 z = {0, 0, 0, 0}; acc[i] = z; }
#pragma unroll
    for (int ks = 0; ks < 8; ++ks) {
        i32x4 a = *(const i32x4*)(S8 + (((ks << 6) + lane) << 4));
#pragma unroll
        for (int i = 0; i < NFR; ++i) {
            i32x4 b = *(const i32x4*)(pk + (((nf0 + i) * 8 + ks) << 10) + (lane << 4));
            acc[i] = MFMA8(a, b, acc[i]);
        }
    }
}

// i8 LDS offset for element (row r in [0,16), col/k c in [0,512))
__device__ __forceinline__ int s8off(int r, int c)
{
    return ((c >> 6) << 10) + (((r & 15) | (((c & 63) >> 4) << 4)) << 4) + (c & 15);
}

// ---------------------------------------------------------------------------
// GRU gh streamer, 2-term, 4 frags/gate: r/z accumulate into accRZ[8]
// (= giacc[0..7], MFMA C-in), n-gate into separate accN[4].
// ---------------------------------------------------------------------------
template<int KS, int STRIDE>
__device__ __forceinline__ void mm_gh4(const bf16* __restrict__ pk, int nf0, int lane,
                                       const bf16* __restrict__ S,
                                       f32x4* accRZ, f32x4* accN)
{
#pragma unroll
    for (int i = 0; i < 4; ++i) { f32x4 z = {0.f, 0.f, 0.f, 0.f}; accN[i] = z; }
#pragma unroll 2
    for (int ks = 0; ks < KS; ++ks) {
        bf16x8 ah = *(const bf16x8*)(S + ((ks << 6) + lane) * 8);
        bf16x8 al = *(const bf16x8*)(S + 8192 + ((ks << 6) + lane) * 8);
#pragma unroll
        for (int i = 0; i < 8; ++i) {
            int nf = (i >> 2) * STRIDE + nf0 + (i & 3);
            bf16x8 bh = *(const bf16x8*)(pk + ((nf * KS + ks) << 9) + (lane << 3));
            accRZ[i] = MFMA(ah, bh, accRZ[i]);
            accRZ[i] = MFMA(al, bh, accRZ[i]);
        }
#pragma unroll
        for (int i = 0; i < 4; ++i) {
            int nf = 2 * STRIDE + nf0 + i;
            bf16x8 bh = *(const bf16x8*)(pk + ((nf * KS + ks) << 9) + (lane << 3));
            accN[i] = MFMA(ah, bh, accN[i]);
            accN[i] = MFMA(al, bh, accN[i]);
        }
    }
}

// 3-term streamer (final mu/logvar projection only): hi*hi + lo*hi + hi*lo.
template<int NFR, int KS, int NFtot, int STRIDE>
__device__ __forceinline__ void mm_stream(const bf16* __restrict__ pk, int nf0, int lane,
                                          const bf16* __restrict__ S, f32x4* acc)
{
    const int halfoff = NFtot * KS * 512;
#pragma unroll
    for (int i = 0; i < NFR; ++i) { f32x4 z = {0.f, 0.f, 0.f, 0.f}; acc[i] = z; }
#pragma unroll 2
    for (int ks = 0; ks < KS; ++ks) {
        bf16x8 ah = *(const bf16x8*)(S + ((ks << 6) + lane) * 8);
        bf16x8 al = *(const bf16x8*)(S + 8192 + ((ks << 6) + lane) * 8);
#pragma unroll
        for (int i = 0; i < NFR; ++i) {
            int nf = (i >> 1) * STRIDE + nf0 + (i & 1);
            const bf16* pb = pk + ((nf * KS + ks) << 9) + (lane << 3);
            bf16x8 bh = *(const bf16x8*)pb;
            bf16x8 bl = *(const bf16x8*)(pb + halfoff);
            acc[i] = MFMA(ah, bh, acc[i]);
            acc[i] = MFMA(al, bh, acc[i]);
            acc[i] = MFMA(ah, bl, acc[i]);
        }
    }
}

// A-frags from registers (K=128 x-input for the GRU gi GEMM), KS=4.
// Single-term: bf16(x) @ Wih_hi^T; 12 accumulators (r0-3, z0-3, n0-3).
template<int STRIDE>
__device__ __forceinline__ void mm_x12(const bf16* __restrict__ pk, int nf0, int lane,
                                       const bf16x8* xh, f32x4* acc)
{
    const int KS = 4;
#pragma unroll
    for (int i = 0; i < 12; ++i) { f32x4 z = {0.f, 0.f, 0.f, 0.f}; acc[i] = z; }
#pragma unroll
    for (int ks = 0; ks < 4; ++ks)
#pragma unroll
        for (int i = 0; i < 12; ++i) {
            int nf = (i >> 2) * STRIDE + nf0 + (i & 3);
            const bf16* pb = pk + ((nf * KS + ks) << 9) + (lane << 3);
            bf16x8 bh = *(const bf16x8*)pb;
            acc[i] = MFMA(xh[ks], bh, acc[i]);
        }
}

// scatter one f32 value (tile row r in [0,16), col c in [0,512)) into split LDS S
__device__ __forceinline__ void scat(bf16* __restrict__ Sp, int r, int c, float v)
{
    bf16 hb = (bf16)v;
    bf16 lb = (bf16)(v - (float)hb);
    int off = (((c >> 5) << 6) + (r | (((c & 31) >> 3) << 4))) * 8 + (c & 7);
    Sp[off] = hb;
    Sp[8192 + off] = lb;
}

// A-side quantization constants: |A| = |h + alpha*k| bounded ~1.35 < 2.5
#define QA_INV 50.8f            /* 127 / 2.5 */
#define QA_S   (2.5f / 127.f)
#define QT_INV 127.f            /* tanh in (-1,1) */
#define QT_S   (1.f / 127.f)

// ---------------------------------------------------------------------------
// Persistent kernel: 64 blocks x 512 threads (8 waves -> 128-VGPR tier, the
// round-3-measured allocation). Block owns 16 batch rows; wave owns 64 output
// cols (4 nf frags). h in LDS for the whole 128-step recurrence. Zero grid
// sync. ODE all-i8, S8 double-buffered, 2 barriers/f-eval (round-13 proven).
// ---------------------------------------------------------------------------
__global__ __launch_bounds__(512, 2)
void odegru_persist(const float* __restrict__ x, const float* __restrict__ t,
                    const float* __restrict__ bih, const float* __restrict__ bhh,
                    const float* __restrict__ b1,  const float* __restrict__ b2,
                    const float* __restrict__ bmu, const float* __restrict__ blv,
                    const int8_t* __restrict__ pkW1, const int8_t* __restrict__ pkW2,
                    const float* __restrict__ sW1, const float* __restrict__ sW2,
                    const bf16* __restrict__ pkWhh, const bf16* __restrict__ pkWih,
                    const bf16* __restrict__ pkWout, float* __restrict__ out)
{
    __shared__ float  hbuf[16 * 512];       // h, f32 [row][col]      (32 KB)
    __shared__ bf16   S[2 * 16 * 64 * 8];   // split(h) for GRU/out   (32 KB)
    __shared__ int8_t S8a[8 * 64 * 16];     // i8 A operand (h side)   (8 KB)
    __shared__ int8_t S8b[8 * 64 * 16];     // i8 tanh operand         (8 KB)
    __shared__ float  odeC[4][512];         // s1,b1,s2,b2             (8 KB)
    __shared__ float  gruB[4][512];         // r-bias,z-bias,bin,bhn   (8 KB)

    const int tid  = threadIdx.x;
    const int lane = tid & 63;
    const int w    = tid >> 6;              // wave 0..7
    const int li   = lane & 15, lh = lane >> 4;
    const int m0   = blockIdx.x << 4;       // batch-row base
    const int Tn = 128, In = 128;

    const int c0 = (w << 6) + li;           // wave's first output col + lane col
    const int rb = lh << 2;                 // C-frag row base
    const int nf0 = w << 2;                 // wave's first frag (of 32)

    {
        int c = tid;                        // 512 threads cover all 512 cols
        odeC[0][c] = sW1[c] * QA_S;
        odeC[1][c] = b1[c];
        odeC[2][c] = sW2[c] * QT_S;
        odeC[3][c] = b2[c];
        gruB[0][c] = bih[c] + bhh[c];
        gruB[1][c] = bih[512 + c] + bhh[512 + c];
        gruB[2][c] = bih[1024 + c];
        gruB[3][c] = bhh[1024 + c];
    }
    __syncthreads();

    i32x4 acc8[4];
    float ksum[4][4];
    f32x4 giacc[12], ghn[4];

    for (int s = 0; s < 128; ++s) {
        const float dt = (s > 0) ? (t[s] - t[s - 1]) : 0.f;
        if (s > 0) {
            const float a01 = dt * 0.125f, a2 = dt * 0.25f, hk = dt * (1.f / 24.f);
#pragma unroll 1
            for (int sub = 0; sub < 4; ++sub) {
#pragma unroll 1
                for (int st = 0; st < 4; ++st) {
                    // fused A+B: tmp_int = qA @ qW1^T; tanh -> S8b (own cols)
                    mm_i8n<4>(pkW1, nf0, lane, S8a, acc8);
#pragma unroll
                    for (int fi = 0; fi < 4; ++fi) {
                        int c = c0 + (fi << 4);
                        float s1 = odeC[0][c], bv = odeC[1][c];
#pragma unroll
                        for (int rg = 0; rg < 4; ++rg) {
                            float v = tanhf((float)acc8[fi][rg] * s1 + bv);
                            S8b[s8off(rb + rg, c)] = (int8_t)__float2int_rn(v * QT_INV);
                        }
                    }
                    __syncthreads();
                    // fused C+D: k_int = q(tmp) @ qW2^T; RK4 -> S8a (or S)
                    mm_i8n<4>(pkW2, nf0, lane, S8b, acc8);
                    {
                        const float al = (st < 2) ? a01 : a2;
#pragma unroll
                        for (int fi = 0; fi < 4; ++fi) {
                            int c = c0 + (fi << 4);
                            float s2 = odeC[2][c], bv = odeC[3][c];
#pragma unroll
                            for (int rg = 0; rg < 4; ++rg) {
                                float v = (float)acc8[fi][rg] * s2 + bv;
                                int hoff = (rb + rg) * 512 + c;
                                if (st == 0) ksum[fi][rg] = v;
                                else if (st < 3) ksum[fi][rg] += 2.f * v;
                                float nv;
                                if (st < 3) {
                                    nv = hbuf[hoff] + al * v;
                                } else {
                                    nv = hbuf[hoff] + hk * (ksum[fi][rg] + v);
                                    hbuf[hoff] = nv;
                                }
                                if (st == 3 && sub == 3) {
                                    scat(S, rb + rg, c, nv);   // h_evolved for GRU gh
                                } else {
                                    float qv = fminf(fmaxf(nv * QA_INV, -127.f), 127.f);
                                    S8a[s8off(rb + rg, c)] = (int8_t)__float2int_rn(qv);
                                }
                            }
                        }
                    }
                    __syncthreads();
                }
            }
        }
        // phase E: gi = bf16(x_s) @ Wih_hi^T  (1-term; 12 accumulators)
        {
            bf16x8 xh[4];
            const float* xp = x + ((long)(m0 + li) * Tn + s) * In + (lh << 3);
#pragma unroll
            for (int ks = 0; ks < 4; ++ks) {
                f32x4 v0 = *(const f32x4*)(xp + (ks << 5));
                f32x4 v1 = *(const f32x4*)(xp + (ks << 5) + 4);
                bf16x8 h8v;
#pragma unroll
                for (int j = 0; j < 4; ++j) {
                    h8v[j]     = (bf16)v0[j];
                    h8v[4 + j] = (bf16)v1[j];
                }
                xh[ks] = h8v;
            }
            mm_x12<32>(pkWih, nf0, lane, xh, giacc);
        }
        // phase F: gh = h @ Whh^T; r/z accumulate into giacc[0..7], n separate
        if (s > 0) {
            mm_gh4<16, 32>(pkWhh, nf0, lane, S, giacc, ghn);
        } else {
#pragma unroll
            for (int i = 0; i < 4; ++i) { f32x4 z = {0.f, 0.f, 0.f, 0.f}; ghn[i] = z; }
        }
        __syncthreads();
        // phase G: GRU gates; h <- (1-z)*n + z*h; S = split(h), S8a = q(h)
#pragma unroll
        for (int fi = 0; fi < 4; ++fi) {
            int c = c0 + (fi << 4);
            float brz = gruB[0][c], bzz = gruB[1][c];
            float bin_ = gruB[2][c], bhn = gruB[3][c];
#pragma unroll
            for (int rg = 0; rg < 4; ++rg) {
                int hoff = (rb + rg) * 512 + c;
                float gr = giacc[fi][rg] + brz;
                float gz = giacc[4 + fi][rg] + bzz;
                float rr = 1.f / (1.f + __expf(-gr));
                float zz = 1.f / (1.f + __expf(-gz));
                float nn = tanhf(giacc[8 + fi][rg] + bin_ + rr * (ghn[fi][rg] + bhn));
                float hold = (s > 0) ? hbuf[hoff] : 0.f;
                float hn = (1.f - zz) * nn + zz * hold;
                hbuf[hoff] = hn;
                scat(S, rb + rg, c, hn);                       // for final projection
                float qv = fminf(fmaxf(hn * QA_INV, -127.f), 127.f);
                S8a[s8off(rb + rg, c)] = (int8_t)__float2int_rn(qv);  // next phase A
            }
        }
        __syncthreads();
    }
    // final: mu / logvar projections (S = split(h_T)); 8 waves x 1 frag, 3-term
    {
        f32x4 oacc[1];
        mm_stream<1, 16, 8, 0>(pkWout, w, lane, S, oacc);
        const float* bo = (w < 4) ? bmu : blv;
        int cl = ((w & 3) << 4) + li;
        float bv = bo[cl];
        float* ob = out + ((w < 4) ? 0 : 65536);
#pragma unroll
        for (int rg = 0; rg < 4; ++rg)
            ob[(long)(m0 + rb + rg) * 64 + cl] = oacc[0][rg] + bv;
    }
}

extern "C" void kernel_launch(void* const* d_in, const int* in_sizes, int n_in,
                              void* d_out, int out_size, void* d_ws, size_t ws_size,
                              hipStream_t stream)
{
    (void)in_sizes; (void)n_in; (void)out_size; (void)ws_size;
    const float* x   = (const float*)d_in[0];
    const float* t   = (const float*)d_in[1];
    const float* Wih = (const float*)d_in[2];
    const float* Whh = (const float*)d_in[3];
    const float* bih = (const float*)d_in[4];
    const float* bhh = (const float*)d_in[5];
    const float* W1  = (const float*)d_in[6];
    const float* b1  = (const float*)d_in[7];
    const float* W2  = (const float*)d_in[8];
    const float* b2  = (const float*)d_in[9];
    const float* Wmu = (const float*)d_in[10];
    const float* bmu = (const float*)d_in[11];
    const float* Wlv = (const float*)d_in[12];
    const float* blv = (const float*)d_in[13];
    float* out = (float*)d_out;

    char* wsb = (char*)d_ws;
    int8_t* pk8_1 = (int8_t*)wsb;                       // 256 KB
    int8_t* pk8_2 = (int8_t*)(wsb + 262144);            // 256 KB
    float*  sW1   = (float*)(wsb + 524288);             // 2 KB
    float*  sW2   = (float*)(wsb + 526336);             // 2 KB
    bf16* pkhh  = (bf16*)(wsb + (1l << 20));            // 3 MB   (2*1536*512)
    bf16* pkih  = pkhh + 1572864;                       // 0.75 MB (2*1536*128)
    bf16* pkout = pkih + 393216;                        // 0.25 MB (2*128*512)

    pack_i8<<<8, 64, 0, stream>>>(W1, pk8_1, sW1, 512, 512);
    pack_i8<<<8, 64, 0, stream>>>(W2, pk8_2, sW2, 512, 512);
    pack_split<<<3072, 256, 0, stream>>>(Whh, pkhh, 1536, 512, 96, 0);
    pack_split<<<768,  256, 0, stream>>>(Wih, pkih, 1536, 128, 96, 0);
    pack_split<<<128,  256, 0, stream>>>(Wmu, pkout, 64, 512, 8, 0);
    pack_split<<<128,  256, 0, stream>>>(Wlv, pkout, 64, 512, 8, 4);

    odegru_persist<<<64, 512, 0, stream>>>(x, t, bih, bhh, b1, b2, bmu, blv,
                                           pk8_1, pk8_2, sW1, sW2,
                                           pkhh, pkih, pkout, out);
}

// Round 16
// 24179.558 us; speedup vs baseline: 1.3896x; 1.3896x over previous
//
#include <hip/hip_runtime.h>
#include <stdint.h>

typedef __bf16 bf16;
typedef __bf16 bf16x8 __attribute__((ext_vector_type(8)));
typedef float f32x4 __attribute__((ext_vector_type(4)));
typedef int   i32x4 __attribute__((ext_vector_type(4)));

// ---------------------------------------------------------------------------
// bf16 split pre-pack (GRU + output weights): f32 [N,K] -> hi/lo bf16 in MFMA
// B-frag layout: pk[half][nf][ks][lane][8], lane=(n&15)|(((k&31)>>3)<<4).
// ---------------------------------------------------------------------------
__global__ void pack_split(const float* __restrict__ src, bf16* __restrict__ dst,
                           int N, int K, int NFtot, int nfBase)
{
    int gid = blockIdx.x * 256 + threadIdx.x;
    if (gid >= N * K) return;
    int n = gid / K, k = gid - n * K;
    int KS = K >> 5;
    float x = src[gid];
    bf16 hb = (bf16)x;                    // RNE
    bf16 lb = (bf16)(x - (float)hb);      // residual (exact in f32)
    int nf = nfBase + (n >> 4);
    int l  = (n & 15) | (((k & 31) >> 3) << 4);
    int ks = k >> 5;
    int e  = k & 7;
    int base = ((nf * KS + ks) << 9) + (l << 3) + e;
    int half = NFtot * KS * 512;
    dst[base] = hb;
    dst[half + base] = lb;
}

// ---------------------------------------------------------------------------
// i8 pre-pack (ODE weights) for v_mfma_i32_16x16x64_i8 B-frags:
// lane = (n&15) | (((k&63)>>4)<<4), e = k&15, ks64 = k>>6.
// Per-output-column scale s[n] = max|W[n,:]|/127.
// ---------------------------------------------------------------------------
__global__ void pack_i8(const float* __restrict__ src, int8_t* __restrict__ dst,
                        float* __restrict__ scale, int N, int K)
{
    int n = blockIdx.x * 64 + threadIdx.x;
    if (n >= N) return;
    const float* row = src + (long)n * K;
    float m = 0.f;
    for (int k = 0; k < K; ++k) m = fmaxf(m, fabsf(row[k]));
    float s = (m > 0.f) ? (m / 127.f) : 1.f;
    scale[n] = s;
    float inv = 1.f / s;
    int KS64 = K >> 6;
    int nf = n >> 4;
    for (int k = 0; k < K; ++k) {
        int q = __float2int_rn(row[k] * inv);
        int l = (n & 15) | (((k & 63) >> 4) << 4);
        dst[((nf * KS64 + (k >> 6)) << 10) + (l << 4) + (k & 15)] = (int8_t)q;
    }
}

#define MFMA(a, b, c)  __builtin_amdgcn_mfma_f32_16x16x32_bf16(a, b, c, 0, 0, 0)
#define MFMA8(a, b, c) __builtin_amdgcn_mfma_i32_16x16x64_i8(a, b, c, 0, 0, 0)

// ---------------------------------------------------------------------------
// ODE streamer, all-i8: acc_int[i] += qA @ qW[nf0+i]^T  (exact int arithmetic).
// K=512 -> 8 iters of K=64. S8: [ks64][lane][16B]; W frag 16B/lane coalesced.
// ---------------------------------------------------------------------------
template<int NFR>
__device__ __forceinline__ void mm_i8n(const int8_t* __restrict__ pk, int nf0, int lane,
                                       const int8_t* __restrict__ S8, i32x4* acc)
{
#pragma unroll
    for (int i = 0; i < NFR; ++i) { i32x4 z = {0, 0, 0, 0}; acc[i] = z; }
#pragma unroll
    for (int ks = 0; ks < 8; ++ks) {
        i32x4 a = *(const i32x4*)(S8 + (((ks << 6) + lane) << 4));
#pragma unroll
        for (int i = 0; i < NFR; ++i) {
            i32x4 b = *(const i32x4*)(pk + (((nf0 + i) * 8 + ks) << 10) + (lane << 4));
            acc[i] = MFMA8(a, b, acc[i]);
        }
    }
}

// i8 LDS offset for element (row r in [0,16), col/k c in [0,512))
__device__ __forceinline__ int s8off(int r, int c)
{
    return ((c >> 6) << 10) + (((r & 15) | (((c & 63) >> 4) << 4)) << 4) + (c & 15);
}

// ---------------------------------------------------------------------------
// GRU gh pass 1 (r,z gates): accumulate into acc[0..3] (MFMA C-in), 2-term.
// acc[0..1] = r frags (nf0, nf0+1), acc[2..3] = z frags (STRIDE+nf0, +1).
// Max 16 accumulator regs live.
// ---------------------------------------------------------------------------
template<int KS, int STRIDE>
__device__ __forceinline__ void mm_gh_rz(const bf16* __restrict__ pk, int nf0, int lane,
                                         const bf16* __restrict__ S, f32x4* acc)
{
#pragma unroll 2
    for (int ks = 0; ks < KS; ++ks) {
        bf16x8 ah = *(const bf16x8*)(S + ((ks << 6) + lane) * 8);
        bf16x8 al = *(const bf16x8*)(S + 8192 + ((ks << 6) + lane) * 8);
#pragma unroll
        for (int i = 0; i < 4; ++i) {
            int nf = (i >> 1) * STRIDE + nf0 + (i & 1);
            bf16x8 bh = *(const bf16x8*)(pk + ((nf * KS + ks) << 9) + (lane << 3));
            acc[i] = MFMA(ah, bh, acc[i]);
            acc[i] = MFMA(al, bh, acc[i]);
        }
    }
}

// GRU gh pass 2 (n gate): fresh acc[0..1], frags 2*STRIDE+nf0..+1. 2-term.
template<int KS, int STRIDE>
__device__ __forceinline__ void mm_gh_n(const bf16* __restrict__ pk, int nf0, int lane,
                                        const bf16* __restrict__ S, f32x4* acc)
{
#pragma unroll
    for (int i = 0; i < 2; ++i) { f32x4 z = {0.f, 0.f, 0.f, 0.f}; acc[i] = z; }
#pragma unroll 2
    for (int ks = 0; ks < KS; ++ks) {
        bf16x8 ah = *(const bf16x8*)(S + ((ks << 6) + lane) * 8);
        bf16x8 al = *(const bf16x8*)(S + 8192 + ((ks << 6) + lane) * 8);
#pragma unroll
        for (int i = 0; i < 2; ++i) {
            int nf = 2 * STRIDE + nf0 + i;
            bf16x8 bh = *(const bf16x8*)(pk + ((nf * KS + ks) << 9) + (lane << 3));
            acc[i] = MFMA(ah, bh, acc[i]);
            acc[i] = MFMA(al, bh, acc[i]);
        }
    }
}

// 3-term streamer (final mu/logvar projection only): hi*hi + lo*hi + hi*lo.
template<int NFR, int KS, int NFtot, int STRIDE>
__device__ __forceinline__ void mm_stream(const bf16* __restrict__ pk, int nf0, int lane,
                                          const bf16* __restrict__ S, f32x4* acc)
{
    const int halfoff = NFtot * KS * 512;
#pragma unroll
    for (int i = 0; i < NFR; ++i) { f32x4 z = {0.f, 0.f, 0.f, 0.f}; acc[i] = z; }
#pragma unroll 2
    for (int ks = 0; ks < KS; ++ks) {
        bf16x8 ah = *(const bf16x8*)(S + ((ks << 6) + lane) * 8);
        bf16x8 al = *(const bf16x8*)(S + 8192 + ((ks << 6) + lane) * 8);
#pragma unroll
        for (int i = 0; i < NFR; ++i) {
            int nf = (i >> 1) * STRIDE + nf0 + (i & 1);
            const bf16* pb = pk + ((nf * KS + ks) << 9) + (lane << 3);
            bf16x8 bh = *(const bf16x8*)pb;
            bf16x8 bl = *(const bf16x8*)(pb + halfoff);
            acc[i] = MFMA(ah, bh, acc[i]);
            acc[i] = MFMA(al, bh, acc[i]);
            acc[i] = MFMA(ah, bl, acc[i]);
        }
    }
}

// gi partial from registers (K=128 x-input), KS=4, single-term bf16(x)@W_hi.
// NFRAGS frags starting at gate-strided positions given by SEL (0:r/z pair
// layout acc[0..3]; 1: n-gate acc[0..1]).
template<int STRIDE>
__device__ __forceinline__ void mm_x_rz(const bf16* __restrict__ pk, int nf0, int lane,
                                        const bf16x8* xh, f32x4* acc)
{
    const int KS = 4;
#pragma unroll
    for (int i = 0; i < 4; ++i) { f32x4 z = {0.f, 0.f, 0.f, 0.f}; acc[i] = z; }
#pragma unroll
    for (int ks = 0; ks < 4; ++ks)
#pragma unroll
        for (int i = 0; i < 4; ++i) {
            int nf = (i >> 1) * STRIDE + nf0 + (i & 1);
            const bf16* pb = pk + ((nf * KS + ks) << 9) + (lane << 3);
            bf16x8 bh = *(const bf16x8*)pb;
            acc[i] = MFMA(xh[ks], bh, acc[i]);
        }
}

template<int STRIDE>
__device__ __forceinline__ void mm_x_n(const bf16* __restrict__ pk, int nf0, int lane,
                                       const bf16x8* xh, f32x4* acc)
{
    const int KS = 4;
#pragma unroll
    for (int i = 0; i < 2; ++i) { f32x4 z = {0.f, 0.f, 0.f, 0.f}; acc[i] = z; }
#pragma unroll
    for (int ks = 0; ks < 4; ++ks)
#pragma unroll
        for (int i = 0; i < 2; ++i) {
            int nf = 2 * STRIDE + nf0 + i;
            const bf16* pb = pk + ((nf * KS + ks) << 9) + (lane << 3);
            bf16x8 bh = *(const bf16x8*)pb;
            acc[i] = MFMA(xh[ks], bh, acc[i]);
        }
}

// load this thread's x-fragments (bf16, 1-term) for step s
__device__ __forceinline__ void load_x(const float* __restrict__ x, int m0, int li,
                                       int lh, int s, bf16x8* xh)
{
    const float* xp = x + ((long)(m0 + li) * 128 + s) * 128 + (lh << 3);
#pragma unroll
    for (int ks = 0; ks < 4; ++ks) {
        f32x4 v0 = *(const f32x4*)(xp + (ks << 5));
        f32x4 v1 = *(const f32x4*)(xp + (ks << 5) + 4);
        bf16x8 h8v;
#pragma unroll
        for (int j = 0; j < 4; ++j) {
            h8v[j]     = (bf16)v0[j];
            h8v[4 + j] = (bf16)v1[j];
        }
        xh[ks] = h8v;
    }
}

// scatter one f32 value (tile row r in [0,16), col c in [0,512)) into split LDS S
__device__ __forceinline__ void scat(bf16* __restrict__ Sp, int r, int c, float v)
{
    bf16 hb = (bf16)v;
    bf16 lb = (bf16)(v - (float)hb);
    int off = (((c >> 5) << 6) + (r | (((c & 31) >> 3) << 4))) * 8 + (c & 7);
    Sp[off] = hb;
    Sp[8192 + off] = lb;
}

// A-side quantization constants: |A| = |h + alpha*k| bounded ~1.35 < 2.5
#define QA_INV 50.8f            /* 127 / 2.5 */
#define QA_S   (2.5f / 127.f)
#define QT_INV 127.f            /* tanh in (-1,1) */
#define QT_S   (1.f / 127.f)

// ---------------------------------------------------------------------------
// Persistent kernel: 64 blocks x 1024 threads (16 waves). Block owns 16 batch
// rows; h in LDS for the whole 128-step recurrence. Zero grid sync.
// ODE all-i8, S8 double-buffered, 2 barriers/f-eval (round-13 proven).
// Round-16: GRU split into RZ-pass + N-pass so <=24 accumulator regs are
// live at once (kills the 41-dword/thread/step GRU register spill).
// ---------------------------------------------------------------------------
__global__ __launch_bounds__(1024, 4)
void odegru_persist(const float* __restrict__ x, const float* __restrict__ t,
                    const float* __restrict__ bih, const float* __restrict__ bhh,
                    const float* __restrict__ b1,  const float* __restrict__ b2,
                    const float* __restrict__ bmu, const float* __restrict__ blv,
                    const int8_t* __restrict__ pkW1, const int8_t* __restrict__ pkW2,
                    const float* __restrict__ sW1, const float* __restrict__ sW2,
                    const bf16* __restrict__ pkWhh, const bf16* __restrict__ pkWih,
                    const bf16* __restrict__ pkWout, float* __restrict__ out)
{
    __shared__ float  hbuf[16 * 512];       // h, f32 [row][col]      (32 KB)
    __shared__ bf16   S[2 * 16 * 64 * 8];   // split(h) for GRU/out   (32 KB)
    __shared__ int8_t S8a[8 * 64 * 16];     // i8 A operand (h side)   (8 KB)
    __shared__ int8_t S8b[8 * 64 * 16];     // i8 tanh operand         (8 KB)
    __shared__ float  odeC[4][512];         // s1,b1,s2,b2             (8 KB)
    __shared__ float  gruB[4][512];         // r-bias,z-bias,bin,bhn   (8 KB)

    const int tid  = threadIdx.x;
    const int lane = tid & 63;
    const int w    = tid >> 6;              // wave 0..15
    const int li   = lane & 15, lh = lane >> 4;
    const int m0   = blockIdx.x << 4;       // batch-row base

    const int c0 = (w << 5) + li;           // wave's first output col + lane col
    const int rb = lh << 2;                 // C-frag row base

    if (tid < 512) {
        int c = tid;
        odeC[0][c] = sW1[c] * QA_S;
        odeC[1][c] = b1[c];
        odeC[2][c] = sW2[c] * QT_S;
        odeC[3][c] = b2[c];
        gruB[0][c] = bih[c] + bhh[c];
        gruB[1][c] = bih[512 + c] + bhh[512 + c];
        gruB[2][c] = bih[1024 + c];
        gruB[3][c] = bhh[1024 + c];
    }
    __syncthreads();

    i32x4 acc8[2];
    float ksum[2][4];
    f32x4 racc[2], zacc[2], ginacc[2], ghnacc[2];

    for (int s = 0; s < 128; ++s) {
        const float dt = (s > 0) ? (t[s] - t[s - 1]) : 0.f;
        if (s > 0) {
            const float a01 = dt * 0.125f, a2 = dt * 0.25f, hk = dt * (1.f / 24.f);
#pragma unroll 1
            for (int sub = 0; sub < 4; ++sub) {
#pragma unroll 1
                for (int st = 0; st < 4; ++st) {
                    // fused A+B: tmp_int = qA @ qW1^T; tanh -> S8b (own cols)
                    mm_i8n<2>(pkW1, w << 1, lane, S8a, acc8);
#pragma unroll
                    for (int fi = 0; fi < 2; ++fi) {
                        int c = c0 + (fi << 4);
                        float s1 = odeC[0][c], bv = odeC[1][c];
#pragma unroll
                        for (int rg = 0; rg < 4; ++rg) {
                            float v = tanhf((float)acc8[fi][rg] * s1 + bv);
                            S8b[s8off(rb + rg, c)] = (int8_t)__float2int_rn(v * QT_INV);
                        }
                    }
                    __syncthreads();
                    // fused C+D: k_int = q(tmp) @ qW2^T; RK4 -> S8a (or S)
                    mm_i8n<2>(pkW2, w << 1, lane, S8b, acc8);
                    {
                        const float al = (st < 2) ? a01 : a2;
#pragma unroll
                        for (int fi = 0; fi < 2; ++fi) {
                            int c = c0 + (fi << 4);
                            float s2 = odeC[2][c], bv = odeC[3][c];
#pragma unroll
                            for (int rg = 0; rg < 4; ++rg) {
                                float v = (float)acc8[fi][rg] * s2 + bv;
                                int hoff = (rb + rg) * 512 + c;
                                if (st == 0) ksum[fi][rg] = v;
                                else if (st < 3) ksum[fi][rg] += 2.f * v;
                                float nv;
                                if (st < 3) {
                                    nv = hbuf[hoff] + al * v;
                                } else {
                                    nv = hbuf[hoff] + hk * (ksum[fi][rg] + v);
                                    hbuf[hoff] = nv;
                                }
                                if (st == 3 && sub == 3) {
                                    scat(S, rb + rg, c, nv);   // h_evolved for GRU gh
                                } else {
                                    float qv = fminf(fmaxf(nv * QA_INV, -127.f), 127.f);
                                    S8a[s8off(rb + rg, c)] = (int8_t)__float2int_rn(qv);
                                }
                            }
                        }
                    }
                    __syncthreads();
                }
            }
        }
        // ---- GRU pass RZ: gr,gz = x@Wih + h@Whh (r,z slices) -> r,z in regs
        {
            f32x4 grz[4];
            {
                bf16x8 xh[4];
                load_x(x, m0, li, lh, s, xh);
                mm_x_rz<32>(pkWih, w << 1, lane, xh, grz);
            }
            if (s > 0) mm_gh_rz<16, 32>(pkWhh, w << 1, lane, S, grz);
#pragma unroll
            for (int fi = 0; fi < 2; ++fi) {
                int c = c0 + (fi << 4);
                float brz = gruB[0][c], bzz = gruB[1][c];
#pragma unroll
                for (int rg = 0; rg < 4; ++rg) {
                    racc[fi][rg] = 1.f / (1.f + __expf(-(grz[fi][rg] + brz)));
                    zacc[fi][rg] = 1.f / (1.f + __expf(-(grz[2 + fi][rg] + bzz)));
                }
            }
        }
        // ---- GRU pass N: gi_n and gh_n (separate accumulators)
        {
            bf16x8 xh[4];
            load_x(x, m0, li, lh, s, xh);
            mm_x_n<32>(pkWih, w << 1, lane, xh, ginacc);
        }
        if (s > 0) {
            mm_gh_n<16, 32>(pkWhh, w << 1, lane, S, ghnacc);
        } else {
#pragma unroll
            for (int i = 0; i < 2; ++i) { f32x4 z = {0.f, 0.f, 0.f, 0.f}; ghnacc[i] = z; }
        }
        __syncthreads();
        // ---- G: gates; h <- (1-z)*n + z*h; S = split(h), S8a = q(h)
#pragma unroll
        for (int fi = 0; fi < 2; ++fi) {
            int c = c0 + (fi << 4);
            float bin_ = gruB[2][c], bhn = gruB[3][c];
#pragma unroll
            for (int rg = 0; rg < 4; ++rg) {
                int hoff = (rb + rg) * 512 + c;
                float nn = tanhf(ginacc[fi][rg] + bin_ +
                                 racc[fi][rg] * (ghnacc[fi][rg] + bhn));
                float zz = zacc[fi][rg];
                float hold = (s > 0) ? hbuf[hoff] : 0.f;
                float hn = (1.f - zz) * nn + zz * hold;
                hbuf[hoff] = hn;
                scat(S, rb + rg, c, hn);                       // for final projection
                float qv = fminf(fmaxf(hn * QA_INV, -127.f), 127.f);
                S8a[s8off(rb + rg, c)] = (int8_t)__float2int_rn(qv);  // next phase A
            }
        }
        __syncthreads();
    }
    // final: mu / logvar projections (S = split(h_T)); waves 0..7, 3-term
    if (w < 8) {
        f32x4 oacc[1];
        mm_stream<1, 16, 8, 0>(pkWout, w, lane, S, oacc);
        const float* bo = (w < 4) ? bmu : blv;
        int cl = ((w & 3) << 4) + li;
        float bv = bo[cl];
        float* ob = out + ((w < 4) ? 0 : 65536);
#pragma unroll
        for (int rg = 0; rg < 4; ++rg)
            ob[(long)(m0 + rb + rg) * 64 + cl] = oacc[0][rg] + bv;
    }
}

extern "C" void kernel_launch(void* const* d_in, const int* in_sizes, int n_in,
                              void* d_out, int out_size, void* d_ws, size_t ws_size,
                              hipStream_t stream)
{
    (void)in_sizes; (void)n_in; (void)out_size; (void)ws_size;
    const float* x   = (const float*)d_in[0];
    const float* t   = (const float*)d_in[1];
    const float* Wih = (const float*)d_in[2];
    const float* Whh = (const float*)d_in[3];
    const float* bih = (const float*)d_in[4];
    const float* bhh = (const float*)d_in[5];
    const float* W1  = (const float*)d_in[6];
    const float* b1  = (const float*)d_in[7];
    const float* W2  = (const float*)d_in[8];
    const float* b2  = (const float*)d_in[9];
    const float* Wmu = (const float*)d_in[10];
    const float* bmu = (const float*)d_in[11];
    const float* Wlv = (const float*)d_in[12];
    const float* blv = (const float*)d_in[13];
    float* out = (float*)d_out;

    char* wsb = (char*)d_ws;
    int8_t* pk8_1 = (int8_t*)wsb;                       // 256 KB
    int8_t* pk8_2 = (int8_t*)(wsb + 262144);            // 256 KB
    float*  sW1   = (float*)(wsb + 524288);             // 2 KB
    float*  sW2   = (float*)(wsb + 526336);             // 2 KB
    bf16* pkhh  = (bf16*)(wsb + (1l << 20));            // 3 MB   (2*1536*512)
    bf16* pkih  = pkhh + 1572864;                       // 0.75 MB (2*1536*128)
    bf16* pkout = pkih + 393216;                        // 0.25 MB (2*128*512)

    pack_i8<<<8, 64, 0, stream>>>(W1, pk8_1, sW1, 512, 512);
    pack_i8<<<8, 64, 0, stream>>>(W2, pk8_2, sW2, 512, 512);
    pack_split<<<3072, 256, 0, stream>>>(Whh, pkhh, 1536, 512, 96, 0);
    pack_split<<<768,  256, 0, stream>>>(Wih, pkih, 1536, 128, 96, 0);
    pack_split<<<128,  256, 0, stream>>>(Wmu, pkout, 64, 512, 8, 0);
    pack_split<<<128,  256, 0, stream>>>(Wlv, pkout, 64, 512, 8, 4);

    odegru_persist<<<64, 1024, 0, stream>>>(x, t, bih, bhh, b1, b2, bmu, blv,
                                            pk8_1, pk8_2, sW1, sW2,
                                            pkhh, pkih, pkout, out);
}

// Round 17
// 23970.667 us; speedup vs baseline: 1.4017x; 1.0087x over previous
//
#include <hip/hip_runtime.h>
#include <stdint.h>

typedef __bf16 bf16;
typedef __bf16 bf16x8 __attribute__((ext_vector_type(8)));
typedef float f32x4 __attribute__((ext_vector_type(4)));
typedef int   i32x4 __attribute__((ext_vector_type(4)));

// ---------------------------------------------------------------------------
// bf16 split pre-pack (GRU + output weights): f32 [N,K] -> hi/lo bf16 in MFMA
// B-frag layout: pk[half][nf][ks][lane][8], lane=(n&15)|(((k&31)>>3)<<4).
// ---------------------------------------------------------------------------
__global__ void pack_split(const float* __restrict__ src, bf16* __restrict__ dst,
                           int N, int K, int NFtot, int nfBase)
{
    int gid = blockIdx.x * 256 + threadIdx.x;
    if (gid >= N * K) return;
    int n = gid / K, k = gid - n * K;
    int KS = K >> 5;
    float x = src[gid];
    bf16 hb = (bf16)x;                    // RNE
    bf16 lb = (bf16)(x - (float)hb);      // residual (exact in f32)
    int nf = nfBase + (n >> 4);
    int l  = (n & 15) | (((k & 31) >> 3) << 4);
    int ks = k >> 5;
    int e  = k & 7;
    int base = ((nf * KS + ks) << 9) + (l << 3) + e;
    int half = NFtot * KS * 512;
    dst[base] = hb;
    dst[half + base] = lb;
}

// ---------------------------------------------------------------------------
// i8 pre-pack (ODE weights) for v_mfma_i32_16x16x64_i8 B-frags:
// lane = (n&15) | (((k&63)>>4)<<4), e = k&15, ks64 = k>>6.
// Per-output-column scale s[n] = max|W[n,:]|/127.
// ---------------------------------------------------------------------------
__global__ void pack_i8(const float* __restrict__ src, int8_t* __restrict__ dst,
                        float* __restrict__ scale, int N, int K)
{
    int n = blockIdx.x * 64 + threadIdx.x;
    if (n >= N) return;
    const float* row = src + (long)n * K;
    float m = 0.f;
    for (int k = 0; k < K; ++k) m = fmaxf(m, fabsf(row[k]));
    float s = (m > 0.f) ? (m / 127.f) : 1.f;
    scale[n] = s;
    float inv = 1.f / s;
    int KS64 = K >> 6;
    int nf = n >> 4;
    for (int k = 0; k < K; ++k) {
        int q = __float2int_rn(row[k] * inv);
        int l = (n & 15) | (((k & 63) >> 4) << 4);
        dst[((nf * KS64 + (k >> 6)) << 10) + (l << 4) + (k & 15)] = (int8_t)q;
    }
}

#define MFMA(a, b, c)  __builtin_amdgcn_mfma_f32_16x16x32_bf16(a, b, c, 0, 0, 0)
#define MFMA8(a, b, c) __builtin_amdgcn_mfma_i32_16x16x64_i8(a, b, c, 0, 0, 0)

// ---------------------------------------------------------------------------
// ODE streamer, all-i8: acc_int[i] += qA @ qW[nf0+i]^T  (exact int arithmetic).
// K=512 -> 8 iters of K=64. S8: [ks64][lane][16B]; W frag 16B/lane coalesced.
// ---------------------------------------------------------------------------
template<int NFR>
__device__ __forceinline__ void mm_i8n(const int8_t* __restrict__ pk, int nf0, int lane,
                                       const int8_t* __restrict__ S8, i32x4* acc)
{
#pragma unroll
    for (int i = 0; i < NFR; ++i) { i32x4 z = {0, 0, 0, 0}; acc[i] = z; }
#pragma unroll
    for (int ks = 0; ks < 8; ++ks) {
        i32x4 a = *(const i32x4*)(S8 + (((ks << 6) + lane) << 4));
#pragma unroll
        for (int i = 0; i < NFR; ++i) {
            i32x4 b = *(const i32x4*)(pk + (((nf0 + i) * 8 + ks) << 10) + (lane << 4));
            acc[i] = MFMA8(a, b, acc[i]);
        }
    }
}

// i8 LDS offset for element (row r in [0,16), col/k c in [0,512))
__device__ __forceinline__ int s8off(int r, int c)
{
    return ((c >> 6) << 10) + (((r & 15) | (((c & 63) >> 4) << 4)) << 4) + (c & 15);
}

// ---------------------------------------------------------------------------
// GRU gh streamer, 2-term, accumulate-in-place: r/z gates add into accRZ
// (= giacc[0..3], MFMA C-in), n-gate into separate accN[2].
// ---------------------------------------------------------------------------
template<int KS, int STRIDE>
__device__ __forceinline__ void mm_gh(const bf16* __restrict__ pk, int nf0, int lane,
                                      const bf16* __restrict__ S,
                                      f32x4* accRZ, f32x4* accN)
{
#pragma unroll
    for (int i = 0; i < 2; ++i) { f32x4 z = {0.f, 0.f, 0.f, 0.f}; accN[i] = z; }
#pragma unroll 2
    for (int ks = 0; ks < KS; ++ks) {
        bf16x8 ah = *(const bf16x8*)(S + ((ks << 6) + lane) * 8);
        bf16x8 al = *(const bf16x8*)(S + 8192 + ((ks << 6) + lane) * 8);
#pragma unroll
        for (int i = 0; i < 4; ++i) {
            int nf = (i >> 1) * STRIDE + nf0 + (i & 1);
            bf16x8 bh = *(const bf16x8*)(pk + ((nf * KS + ks) << 9) + (lane << 3));
            accRZ[i] = MFMA(ah, bh, accRZ[i]);
            accRZ[i] = MFMA(al, bh, accRZ[i]);
        }
#pragma unroll
        for (int i = 0; i < 2; ++i) {
            int nf = 2 * STRIDE + nf0 + i;
            bf16x8 bh = *(const bf16x8*)(pk + ((nf * KS + ks) << 9) + (lane << 3));
            accN[i] = MFMA(ah, bh, accN[i]);
            accN[i] = MFMA(al, bh, accN[i]);
        }
    }
}

// 3-term streamer (final mu/logvar projection only): hi*hi + lo*hi + hi*lo.
template<int NFR, int KS, int NFtot, int STRIDE>
__device__ __forceinline__ void mm_stream(const bf16* __restrict__ pk, int nf0, int lane,
                                          const bf16* __restrict__ S, f32x4* acc)
{
    const int halfoff = NFtot * KS * 512;
#pragma unroll
    for (int i = 0; i < NFR; ++i) { f32x4 z = {0.f, 0.f, 0.f, 0.f}; acc[i] = z; }
#pragma unroll 2
    for (int ks = 0; ks < KS; ++ks) {
        bf16x8 ah = *(const bf16x8*)(S + ((ks << 6) + lane) * 8);
        bf16x8 al = *(const bf16x8*)(S + 8192 + ((ks << 6) + lane) * 8);
#pragma unroll
        for (int i = 0; i < NFR; ++i) {
            int nf = (i >> 1) * STRIDE + nf0 + (i & 1);
            const bf16* pb = pk + ((nf * KS + ks) << 9) + (lane << 3);
            bf16x8 bh = *(const bf16x8*)pb;
            bf16x8 bl = *(const bf16x8*)(pb + halfoff);
            acc[i] = MFMA(ah, bh, acc[i]);
            acc[i] = MFMA(al, bh, acc[i]);
            acc[i] = MFMA(ah, bl, acc[i]);
        }
    }
}

// A-frags from registers (K=128 x-input for the GRU gi GEMM), KS=4.
// Single-term: bf16(x) @ Wih_hi^T (x_lo dropped; validated round 14).
template<int NFR, int STRIDE>
__device__ __forceinline__ void mm_x1(const bf16* __restrict__ pk, int nf0, int lane,
                                      const bf16x8* xh, f32x4* acc)
{
    const int KS = 4;
#pragma unroll
    for (int i = 0; i < NFR; ++i) { f32x4 z = {0.f, 0.f, 0.f, 0.f}; acc[i] = z; }
#pragma unroll
    for (int ks = 0; ks < 4; ++ks)
#pragma unroll
        for (int i = 0; i < NFR; ++i) {
            int nf = (i >> 1) * STRIDE + nf0 + (i & 1);
            const bf16* pb = pk + ((nf * KS + ks) << 9) + (lane << 3);
            bf16x8 bh = *(const bf16x8*)pb;
            acc[i] = MFMA(xh[ks], bh, acc[i]);
        }
}

// scatter one f32 value (tile row r in [0,16), col c in [0,512)) into split LDS S
__device__ __forceinline__ void scat(bf16* __restrict__ Sp, int r, int c, float v)
{
    bf16 hb = (bf16)v;
    bf16 lb = (bf16)(v - (float)hb);
    int off = (((c >> 5) << 6) + (r | (((c & 31) >> 3) << 4))) * 8 + (c & 7);
    Sp[off] = hb;
    Sp[8192 + off] = lb;
}

// A-side quantization constants: |A| = |h + alpha*k| bounded ~1.35 < 2.5
#define QA_INV 50.8f            /* 127 / 2.5 */
#define QA_S   (2.5f / 127.f)
#define QT_INV 127.f            /* tanh in (-1,1) */
#define QT_S   (1.f / 127.f)

// ---------------------------------------------------------------------------
// Persistent kernel: 64 blocks x 1024 threads (16 waves). Block owns 16 batch
// rows; h in LDS for the whole 128-step recurrence. Zero grid sync.
// ODE all-i8, S8 double-buffered, 2 barriers/f-eval.
// Round-17: RK4 ksum moved to LDS (ksbuf) -- it was the only register array
// live across barrier-separated MFMA phases (the 1.35 GB/dispatch spill site).
// ---------------------------------------------------------------------------
__global__ __launch_bounds__(1024, 4)
void odegru_persist(const float* __restrict__ x, const float* __restrict__ t,
                    const float* __restrict__ bih, const float* __restrict__ bhh,
                    const float* __restrict__ b1,  const float* __restrict__ b2,
                    const float* __restrict__ bmu, const float* __restrict__ blv,
                    const int8_t* __restrict__ pkW1, const int8_t* __restrict__ pkW2,
                    const float* __restrict__ sW1, const float* __restrict__ sW2,
                    const bf16* __restrict__ pkWhh, const bf16* __restrict__ pkWih,
                    const bf16* __restrict__ pkWout, float* __restrict__ out)
{
    __shared__ float  hbuf[16 * 512];       // h, f32 [row][col]      (32 KB)
    __shared__ float  ksbuf[16 * 512];      // RK4 ksum, f32          (32 KB)
    __shared__ bf16   S[2 * 16 * 64 * 8];   // split(h) for GRU/out   (32 KB)
    __shared__ int8_t S8a[8 * 64 * 16];     // i8 A operand (h side)   (8 KB)
    __shared__ int8_t S8b[8 * 64 * 16];     // i8 tanh operand         (8 KB)
    __shared__ float  odeC[4][512];         // s1,b1,s2,b2             (8 KB)
    __shared__ float  gruB[4][512];         // r-bias,z-bias,bin,bhn   (8 KB)

    const int tid  = threadIdx.x;
    const int lane = tid & 63;
    const int w    = tid >> 6;              // wave 0..15
    const int li   = lane & 15, lh = lane >> 4;
    const int m0   = blockIdx.x << 4;       // batch-row base
    const int Tn = 128, In = 128;

    const int c0 = (w << 5) + li;           // wave's first output col + lane col
    const int rb = lh << 2;                 // C-frag row base

    if (tid < 512) {
        int c = tid;
        odeC[0][c] = sW1[c] * QA_S;
        odeC[1][c] = b1[c];
        odeC[2][c] = sW2[c] * QT_S;
        odeC[3][c] = b2[c];
        gruB[0][c] = bih[c] + bhh[c];
        gruB[1][c] = bih[512 + c] + bhh[512 + c];
        gruB[2][c] = bih[1024 + c];
        gruB[3][c] = bhh[1024 + c];
    }
    __syncthreads();

    i32x4 acc8[2];
    f32x4 giacc[6], ghn[2];

    for (int s = 0; s < 128; ++s) {
        const float dt = (s > 0) ? (t[s] - t[s - 1]) : 0.f;
        if (s > 0) {
            const float a01 = dt * 0.125f, a2 = dt * 0.25f, hk = dt * (1.f / 24.f);
#pragma unroll 1
            for (int sub = 0; sub < 4; ++sub) {
#pragma unroll 1
                for (int st = 0; st < 4; ++st) {
                    // fused A+B: tmp_int = qA @ qW1^T; tanh -> S8b (own cols)
                    mm_i8n<2>(pkW1, w << 1, lane, S8a, acc8);
#pragma unroll
                    for (int fi = 0; fi < 2; ++fi) {
                        int c = c0 + (fi << 4);
                        float s1 = odeC[0][c], bv = odeC[1][c];
#pragma unroll
                        for (int rg = 0; rg < 4; ++rg) {
                            float v = tanhf((float)acc8[fi][rg] * s1 + bv);
                            S8b[s8off(rb + rg, c)] = (int8_t)__float2int_rn(v * QT_INV);
                        }
                    }
                    __syncthreads();
                    // fused C+D: k_int = q(tmp) @ qW2^T; RK4 -> S8a (or S)
                    mm_i8n<2>(pkW2, w << 1, lane, S8b, acc8);
                    {
                        const float al = (st < 2) ? a01 : a2;
#pragma unroll
                        for (int fi = 0; fi < 2; ++fi) {
                            int c = c0 + (fi << 4);
                            float s2 = odeC[2][c], bv = odeC[3][c];
#pragma unroll
                            for (int rg = 0; rg < 4; ++rg) {
                                float v = (float)acc8[fi][rg] * s2 + bv;
                                int hoff = (rb + rg) * 512 + c;
                                if (st == 0) ksbuf[hoff] = v;
                                else if (st < 3) ksbuf[hoff] += 2.f * v;
                                float nv;
                                if (st < 3) {
                                    nv = hbuf[hoff] + al * v;
                                } else {
                                    nv = hbuf[hoff] + hk * (ksbuf[hoff] + v);
                                    hbuf[hoff] = nv;
                                }
                                if (st == 3 && sub == 3) {
                                    scat(S, rb + rg, c, nv);   // h_evolved for GRU gh
                                } else {
                                    float qv = fminf(fmaxf(nv * QA_INV, -127.f), 127.f);
                                    S8a[s8off(rb + rg, c)] = (int8_t)__float2int_rn(qv);
                                }
                            }
                        }
                    }
                    __syncthreads();
                }
            }
        }
        // phase E: gi = bf16(x_s) @ Wih_hi^T  (1-term; xh only, 16 regs)
        {
            bf16x8 xh[4];
            const float* xp = x + ((long)(m0 + li) * Tn + s) * In + (lh << 3);
#pragma unroll
            for (int ks = 0; ks < 4; ++ks) {
                f32x4 v0 = *(const f32x4*)(xp + (ks << 5));
                f32x4 v1 = *(const f32x4*)(xp + (ks << 5) + 4);
                bf16x8 h8v;
#pragma unroll
                for (int j = 0; j < 4; ++j) {
                    h8v[j]     = (bf16)v0[j];
                    h8v[4 + j] = (bf16)v1[j];
                }
                xh[ks] = h8v;
            }
            mm_x1<6, 32>(pkWih, w << 1, lane, xh, giacc);
        }
        // phase F: gh = h @ Whh^T; r/z accumulate into giacc, n separate
        if (s > 0) {
            mm_gh<16, 32>(pkWhh, w << 1, lane, S, giacc, ghn);
        } else {
#pragma unroll
            for (int i = 0; i < 2; ++i) { f32x4 z = {0.f, 0.f, 0.f, 0.f}; ghn[i] = z; }
        }
        __syncthreads();
        // phase G: GRU gates; h <- (1-z)*n + z*h; S = split(h), S8a = q(h)
#pragma unroll
        for (int fi = 0; fi < 2; ++fi) {
            int c = c0 + (fi << 4);
            float brz = gruB[0][c], bzz = gruB[1][c];
            float bin_ = gruB[2][c], bhn = gruB[3][c];
#pragma unroll
            for (int rg = 0; rg < 4; ++rg) {
                int hoff = (rb + rg) * 512 + c;
                float gr = giacc[fi][rg] + brz;
                float gz = giacc[2 + fi][rg] + bzz;
                float rr = 1.f / (1.f + __expf(-gr));
                float zz = 1.f / (1.f + __expf(-gz));
                float nn = tanhf(giacc[4 + fi][rg] + bin_ + rr * (ghn[fi][rg] + bhn));
                float hold = (s > 0) ? hbuf[hoff] : 0.f;
                float hn = (1.f - zz) * nn + zz * hold;
                hbuf[hoff] = hn;
                scat(S, rb + rg, c, hn);                       // for final projection
                float qv = fminf(fmaxf(hn * QA_INV, -127.f), 127.f);
                S8a[s8off(rb + rg, c)] = (int8_t)__float2int_rn(qv);  // next phase A
            }
        }
        __syncthreads();
    }
    // final: mu / logvar projections (S = split(h_T)); waves 0..7, 3-term
    if (w < 8) {
        f32x4 oacc[1];
        mm_stream<1, 16, 8, 0>(pkWout, w, lane, S, oacc);
        const float* bo = (w < 4) ? bmu : blv;
        int cl = ((w & 3) << 4) + li;
        float bv = bo[cl];
        float* ob = out + ((w < 4) ? 0 : 65536);
#pragma unroll
        for (int rg = 0; rg < 4; ++rg)
            ob[(long)(m0 + rb + rg) * 64 + cl] = oacc[0][rg] + bv;
    }
}

extern "C" void kernel_launch(void* const* d_in, const int* in_sizes, int n_in,
                              void* d_out, int out_size, void* d_ws, size_t ws_size,
                              hipStream_t stream)
{
    (void)in_sizes; (void)n_in; (void)out_size; (void)ws_size;
    const float* x   = (const float*)d_in[0];
    const float* t   = (const float*)d_in[1];
    const float* Wih = (const float*)d_in[2];
    const float* Whh = (const float*)d_in[3];
    const float* bih = (const float*)d_in[4];
    const float* bhh = (const float*)d_in[5];
    const float* W1  = (const float*)d_in[6];
    const float* b1  = (const float*)d_in[7];
    const float* W2  = (const float*)d_in[8];
    const float* b2  = (const float*)d_in[9];
    const float* Wmu = (const float*)d_in[10];
    const float* bmu = (const float*)d_in[11];
    const float* Wlv = (const float*)d_in[12];
    const float* blv = (const float*)d_in[13];
    float* out = (float*)d_out;

    char* wsb = (char*)d_ws;
    int8_t* pk8_1 = (int8_t*)wsb;                       // 256 KB
    int8_t* pk8_2 = (int8_t*)(wsb + 262144);            // 256 KB
    float*  sW1   = (float*)(wsb + 524288);             // 2 KB
    float*  sW2   = (float*)(wsb + 526336);             // 2 KB
    bf16* pkhh  = (bf16*)(wsb + (1l << 20));            // 3 MB   (2*1536*512)
    bf16* pkih  = pkhh + 1572864;                       // 0.75 MB (2*1536*128)
    bf16* pkout = pkih + 393216;                        // 0.25 MB (2*128*512)

    pack_i8<<<8, 64, 0, stream>>>(W1, pk8_1, sW1, 512, 512);
    pack_i8<<<8, 64, 0, stream>>>(W2, pk8_2, sW2, 512, 512);
    pack_split<<<3072, 256, 0, stream>>>(Whh, pkhh, 1536, 512, 96, 0);
    pack_split<<<768,  256, 0, stream>>>(Wih, pkih, 1536, 128, 96, 0);
    pack_split<<<128,  256, 0, stream>>>(Wmu, pkout, 64, 512, 8, 0);
    pack_split<<<128,  256, 0, stream>>>(Wlv, pkout, 64, 512, 8, 4);

    odegru_persist<<<64, 1024, 0, stream>>>(x, t, bih, bhh, b1, b2, bmu, blv,
                                            pk8_1, pk8_2, sW1, sW2,
                                            pkhh, pkih, pkout, out);
}

// Round 18
// 23888.309 us; speedup vs baseline: 1.4065x; 1.0034x over previous
//
#include <hip/hip_runtime.h>
#include <stdint.h>

typedef __bf16 bf16;
typedef __bf16 bf16x8 __attribute__((ext_vector_type(8)));
typedef float f32x4 __attribute__((ext_vector_type(4)));
typedef int   i32x4 __attribute__((ext_vector_type(4)));

#define HSTR 516   // padded stride for hbuf/ksbuf: 516 % 32 = 4 -> 2-way (free)

// ---------------------------------------------------------------------------
// bf16 split pre-pack (GRU + output weights): f32 [N,K] -> hi/lo bf16 in MFMA
// B-frag layout: pk[half][nf][ks][lane][8], lane=(n&15)|(((k&31)>>3)<<4).
// ---------------------------------------------------------------------------
__global__ void pack_split(const float* __restrict__ src, bf16* __restrict__ dst,
                           int N, int K, int NFtot, int nfBase)
{
    int gid = blockIdx.x * 256 + threadIdx.x;
    if (gid >= N * K) return;
    int n = gid / K, k = gid - n * K;
    int KS = K >> 5;
    float x = src[gid];
    bf16 hb = (bf16)x;                    // RNE
    bf16 lb = (bf16)(x - (float)hb);      // residual (exact in f32)
    int nf = nfBase + (n >> 4);
    int l  = (n & 15) | (((k & 31) >> 3) << 4);
    int ks = k >> 5;
    int e  = k & 7;
    int base = ((nf * KS + ks) << 9) + (l << 3) + e;
    int half = NFtot * KS * 512;
    dst[base] = hb;
    dst[half + base] = lb;
}

// ---------------------------------------------------------------------------
// i8 pre-pack (ODE weights) for v_mfma_i32_16x16x64_i8 B-frags:
// lane = (n&15) | (((k&63)>>4)<<4), e = k&15, ks64 = k>>6.
// Per-output-column scale s[n] = max|W[n,:]|/127.
// ---------------------------------------------------------------------------
__global__ void pack_i8(const float* __restrict__ src, int8_t* __restrict__ dst,
                        float* __restrict__ scale, int N, int K)
{
    int n = blockIdx.x * 64 + threadIdx.x;
    if (n >= N) return;
    const float* row = src + (long)n * K;
    float m = 0.f;
    for (int k = 0; k < K; ++k) m = fmaxf(m, fabsf(row[k]));
    float s = (m > 0.f) ? (m / 127.f) : 1.f;
    scale[n] = s;
    float inv = 1.f / s;
    int KS64 = K >> 6;
    int nf = n >> 4;
    for (int k = 0; k < K; ++k) {
        int q = __float2int_rn(row[k] * inv);
        int l = (n & 15) | (((k & 63) >> 4) << 4);
        dst[((nf * KS64 + (k >> 6)) << 10) + (l << 4) + (k & 15)] = (int8_t)q;
    }
}

#define MFMA(a, b, c)  __builtin_amdgcn_mfma_f32_16x16x32_bf16(a, b, c, 0, 0, 0)
#define MFMA8(a, b, c) __builtin_amdgcn_mfma_i32_16x16x64_i8(a, b, c, 0, 0, 0)

// fast tanh via hardware exp: 1 - 2/(e^{2x}+1). Correct limits at +-inf;
// ~1e-6 error, far below the i8 quantization step (1/254) applied right after.
// Replaces ocml tanhf (multi-branch, ~15-20 temps -> the ODE-loop spill site).
__device__ __forceinline__ float fast_tanh(float x)
{
    float e = __expf(2.f * x);
    return 1.f - __fdividef(2.f, e + 1.f);
}

// ---------------------------------------------------------------------------
// ODE streamer, all-i8: acc_int[i] += qA @ qW[nf0+i]^T  (exact int arithmetic).
// K=512 -> 8 iters of K=64. S8: [ks64][lane][16B]; W frag 16B/lane coalesced.
// ---------------------------------------------------------------------------
template<int NFR>
__device__ __forceinline__ void mm_i8n(const int8_t* __restrict__ pk, int nf0, int lane,
                                       const int8_t* __restrict__ S8, i32x4* acc)
{
#pragma unroll
    for (int i = 0; i < NFR; ++i) { i32x4 z = {0, 0, 0, 0}; acc[i] = z; }
#pragma unroll
    for (int ks = 0; ks < 8; ++ks) {
        i32x4 a = *(const i32x4*)(S8 + (((ks << 6) + lane) << 4));
#pragma unroll
        for (int i = 0; i < NFR; ++i) {
            i32x4 b = *(const i32x4*)(pk + (((nf0 + i) * 8 + ks) << 10) + (lane << 4));
            acc[i] = MFMA8(a, b, acc[i]);
        }
    }
}

// i8 LDS offset for element (row r in [0,16), col/k c in [0,512))
__device__ __forceinline__ int s8off(int r, int c)
{
    return ((c >> 6) << 10) + (((r & 15) | (((c & 63) >> 4) << 4)) << 4) + (c & 15);
}

// ---------------------------------------------------------------------------
// GRU gh streamer, 2-term, accumulate-in-place: r/z gates add into accRZ
// (= giacc[0..3], MFMA C-in), n-gate into separate accN[2].
// ---------------------------------------------------------------------------
template<int KS, int STRIDE>
__device__ __forceinline__ void mm_gh(const bf16* __restrict__ pk, int nf0, int lane,
                                      const bf16* __restrict__ S,
                                      f32x4* accRZ, f32x4* accN)
{
#pragma unroll
    for (int i = 0; i < 2; ++i) { f32x4 z = {0.f, 0.f, 0.f, 0.f}; accN[i] = z; }
#pragma unroll 2
    for (int ks = 0; ks < KS; ++ks) {
        bf16x8 ah = *(const bf16x8*)(S + ((ks << 6) + lane) * 8);
        bf16x8 al = *(const bf16x8*)(S + 8192 + ((ks << 6) + lane) * 8);
#pragma unroll
        for (int i = 0; i < 4; ++i) {
            int nf = (i >> 1) * STRIDE + nf0 + (i & 1);
            bf16x8 bh = *(const bf16x8*)(pk + ((nf * KS + ks) << 9) + (lane << 3));
            accRZ[i] = MFMA(ah, bh, accRZ[i]);
            accRZ[i] = MFMA(al, bh, accRZ[i]);
        }
#pragma unroll
        for (int i = 0; i < 2; ++i) {
            int nf = 2 * STRIDE + nf0 + i;
            bf16x8 bh = *(const bf16x8*)(pk + ((nf * KS + ks) << 9) + (lane << 3));
            accN[i] = MFMA(ah, bh, accN[i]);
            accN[i] = MFMA(al, bh, accN[i]);
        }
    }
}

// 3-term streamer (final mu/logvar projection only): hi*hi + lo*hi + hi*lo.
template<int NFR, int KS, int NFtot, int STRIDE>
__device__ __forceinline__ void mm_stream(const bf16* __restrict__ pk, int nf0, int lane,
                                          const bf16* __restrict__ S, f32x4* acc)
{
    const int halfoff = NFtot * KS * 512;
#pragma unroll
    for (int i = 0; i < NFR; ++i) { f32x4 z = {0.f, 0.f, 0.f, 0.f}; acc[i] = z; }
#pragma unroll 2
    for (int ks = 0; ks < KS; ++ks) {
        bf16x8 ah = *(const bf16x8*)(S + ((ks << 6) + lane) * 8);
        bf16x8 al = *(const bf16x8*)(S + 8192 + ((ks << 6) + lane) * 8);
#pragma unroll
        for (int i = 0; i < NFR; ++i) {
            int nf = (i >> 1) * STRIDE + nf0 + (i & 1);
            const bf16* pb = pk + ((nf * KS + ks) << 9) + (lane << 3);
            bf16x8 bh = *(const bf16x8*)pb;
            bf16x8 bl = *(const bf16x8*)(pb + halfoff);
            acc[i] = MFMA(ah, bh, acc[i]);
            acc[i] = MFMA(al, bh, acc[i]);
            acc[i] = MFMA(ah, bl, acc[i]);
        }
    }
}

// A-frags from registers (K=128 x-input for the GRU gi GEMM), KS=4.
// Single-term: bf16(x) @ Wih_hi^T (x_lo dropped; validated round 14).
template<int NFR, int STRIDE>
__device__ __forceinline__ void mm_x1(const bf16* __restrict__ pk, int nf0, int lane,
                                      const bf16x8* xh, f32x4* acc)
{
    const int KS = 4;
#pragma unroll
    for (int i = 0; i < NFR; ++i) { f32x4 z = {0.f, 0.f, 0.f, 0.f}; acc[i] = z; }
#pragma unroll
    for (int ks = 0; ks < 4; ++ks)
#pragma unroll
        for (int i = 0; i < NFR; ++i) {
            int nf = (i >> 1) * STRIDE + nf0 + (i & 1);
            const bf16* pb = pk + ((nf * KS + ks) << 9) + (lane << 3);
            bf16x8 bh = *(const bf16x8*)pb;
            acc[i] = MFMA(xh[ks], bh, acc[i]);
        }
}

// scatter one f32 value (tile row r in [0,16), col c in [0,512)) into split LDS S
__device__ __forceinline__ void scat(bf16* __restrict__ Sp, int r, int c, float v)
{
    bf16 hb = (bf16)v;
    bf16 lb = (bf16)(v - (float)hb);
    int off = (((c >> 5) << 6) + (r | (((c & 31) >> 3) << 4))) * 8 + (c & 7);
    Sp[off] = hb;
    Sp[8192 + off] = lb;
}

// A-side quantization constants: |A| = |h + alpha*k| bounded ~1.35 < 2.5
#define QA_INV 50.8f            /* 127 / 2.5 */
#define QA_S   (2.5f / 127.f)
#define QT_INV 127.f            /* tanh in (-1,1) */
#define QT_S   (1.f / 127.f)

// ---------------------------------------------------------------------------
// Persistent kernel: 64 blocks x 1024 threads (16 waves). Block owns 16 batch
// rows; h in LDS for the whole 128-step recurrence. Zero grid sync.
// ODE all-i8, S8 double-buffered, 2 barriers/f-eval, ksum in LDS.
// Round-18: tanhf -> fast_tanh (__expf; kills ocml's temp-register spill) and
// hbuf/ksbuf padded to stride 516 (4-way -> free 2-way bank access).
// ---------------------------------------------------------------------------
__global__ __launch_bounds__(1024, 4)
void odegru_persist(const float* __restrict__ x, const float* __restrict__ t,
                    const float* __restrict__ bih, const float* __restrict__ bhh,
                    const float* __restrict__ b1,  const float* __restrict__ b2,
                    const float* __restrict__ bmu, const float* __restrict__ blv,
                    const int8_t* __restrict__ pkW1, const int8_t* __restrict__ pkW2,
                    const float* __restrict__ sW1, const float* __restrict__ sW2,
                    const bf16* __restrict__ pkWhh, const bf16* __restrict__ pkWih,
                    const bf16* __restrict__ pkWout, float* __restrict__ out)
{
    __shared__ float  hbuf[16 * HSTR];      // h, f32, padded          (33 KB)
    __shared__ float  ksbuf[16 * HSTR];     // RK4 ksum, padded        (33 KB)
    __shared__ bf16   S[2 * 16 * 64 * 8];   // split(h) for GRU/out    (32 KB)
    __shared__ int8_t S8a[8 * 64 * 16];     // i8 A operand (h side)    (8 KB)
    __shared__ int8_t S8b[8 * 64 * 16];     // i8 tanh operand          (8 KB)
    __shared__ float  odeC[4][512];         // s1,b1,s2,b2              (8 KB)
    __shared__ float  gruB[4][512];         // r-bias,z-bias,bin,bhn    (8 KB)

    const int tid  = threadIdx.x;
    const int lane = tid & 63;
    const int w    = tid >> 6;              // wave 0..15
    const int li   = lane & 15, lh = lane >> 4;
    const int m0   = blockIdx.x << 4;       // batch-row base
    const int Tn = 128, In = 128;

    const int c0 = (w << 5) + li;           // wave's first output col + lane col
    const int rb = lh << 2;                 // C-frag row base

    if (tid < 512) {
        int c = tid;
        odeC[0][c] = sW1[c] * QA_S;
        odeC[1][c] = b1[c];
        odeC[2][c] = sW2[c] * QT_S;
        odeC[3][c] = b2[c];
        gruB[0][c] = bih[c] + bhh[c];
        gruB[1][c] = bih[512 + c] + bhh[512 + c];
        gruB[2][c] = bih[1024 + c];
        gruB[3][c] = bhh[1024 + c];
    }
    __syncthreads();

    i32x4 acc8[2];
    f32x4 giacc[6], ghn[2];

    for (int s = 0; s < 128; ++s) {
        const float dt = (s > 0) ? (t[s] - t[s - 1]) : 0.f;
        if (s > 0) {
            const float a01 = dt * 0.125f, a2 = dt * 0.25f, hk = dt * (1.f / 24.f);
#pragma unroll 1
            for (int sub = 0; sub < 4; ++sub) {
#pragma unroll 1
                for (int st = 0; st < 4; ++st) {
                    // fused A+B: tmp_int = qA @ qW1^T; tanh -> S8b (own cols)
                    mm_i8n<2>(pkW1, w << 1, lane, S8a, acc8);
#pragma unroll
                    for (int fi = 0; fi < 2; ++fi) {
                        int c = c0 + (fi << 4);
                        float s1 = odeC[0][c], bv = odeC[1][c];
#pragma unroll
                        for (int rg = 0; rg < 4; ++rg) {
                            float v = fast_tanh((float)acc8[fi][rg] * s1 + bv);
                            S8b[s8off(rb + rg, c)] = (int8_t)__float2int_rn(v * QT_INV);
                        }
                    }
                    __syncthreads();
                    // fused C+D: k_int = q(tmp) @ qW2^T; RK4 -> S8a (or S)
                    mm_i8n<2>(pkW2, w << 1, lane, S8b, acc8);
                    {
                        const float al = (st < 2) ? a01 : a2;
#pragma unroll
                        for (int fi = 0; fi < 2; ++fi) {
                            int c = c0 + (fi << 4);
                            float s2 = odeC[2][c], bv = odeC[3][c];
#pragma unroll
                            for (int rg = 0; rg < 4; ++rg) {
                                float v = (float)acc8[fi][rg] * s2 + bv;
                                int hoff = (rb + rg) * HSTR + c;
                                if (st == 0) ksbuf[hoff] = v;
                                else if (st < 3) ksbuf[hoff] += 2.f * v;
                                float nv;
                                if (st < 3) {
                                    nv = hbuf[hoff] + al * v;
                                } else {
                                    nv = hbuf[hoff] + hk * (ksbuf[hoff] + v);
                                    hbuf[hoff] = nv;
                                }
                                if (st == 3 && sub == 3) {
                                    scat(S, rb + rg, c, nv);   // h_evolved for GRU gh
                                } else {
                                    float qv = fminf(fmaxf(nv * QA_INV, -127.f), 127.f);
                                    S8a[s8off(rb + rg, c)] = (int8_t)__float2int_rn(qv);
                                }
                            }
                        }
                    }
                    __syncthreads();
                }
            }
        }
        // phase E: gi = bf16(x_s) @ Wih_hi^T  (1-term; xh only, 16 regs)
        {
            bf16x8 xh[4];
            const float* xp = x + ((long)(m0 + li) * Tn + s) * In + (lh << 3);
#pragma unroll
            for (int ks = 0; ks < 4; ++ks) {
                f32x4 v0 = *(const f32x4*)(xp + (ks << 5));
                f32x4 v1 = *(const f32x4*)(xp + (ks << 5) + 4);
                bf16x8 h8v;
#pragma unroll
                for (int j = 0; j < 4; ++j) {
                    h8v[j]     = (bf16)v0[j];
                    h8v[4 + j] = (bf16)v1[j];
                }
                xh[ks] = h8v;
            }
            mm_x1<6, 32>(pkWih, w << 1, lane, xh, giacc);
        }
        // phase F: gh = h @ Whh^T; r/z accumulate into giacc, n separate
        if (s > 0) {
            mm_gh<16, 32>(pkWhh, w << 1, lane, S, giacc, ghn);
        } else {
#pragma unroll
            for (int i = 0; i < 2; ++i) { f32x4 z = {0.f, 0.f, 0.f, 0.f}; ghn[i] = z; }
        }
        __syncthreads();
        // phase G: GRU gates; h <- (1-z)*n + z*h; S = split(h), S8a = q(h)
#pragma unroll
        for (int fi = 0; fi < 2; ++fi) {
            int c = c0 + (fi << 4);
            float brz = gruB[0][c], bzz = gruB[1][c];
            float bin_ = gruB[2][c], bhn = gruB[3][c];
#pragma unroll
            for (int rg = 0; rg < 4; ++rg) {
                int hoff = (rb + rg) * HSTR + c;
                float gr = giacc[fi][rg] + brz;
                float gz = giacc[2 + fi][rg] + bzz;
                float rr = 1.f / (1.f + __expf(-gr));
                float zz = 1.f / (1.f + __expf(-gz));
                float nn = fast_tanh(giacc[4 + fi][rg] + bin_ + rr * (ghn[fi][rg] + bhn));
                float hold = (s > 0) ? hbuf[hoff] : 0.f;
                float hn = (1.f - zz) * nn + zz * hold;
                hbuf[hoff] = hn;
                scat(S, rb + rg, c, hn);                       // for final projection
                float qv = fminf(fmaxf(hn * QA_INV, -127.f), 127.f);
                S8a[s8off(rb + rg, c)] = (int8_t)__float2int_rn(qv);  // next phase A
            }
        }
        __syncthreads();
    }
    // final: mu / logvar projections (S = split(h_T)); waves 0..7, 3-term
    if (w < 8) {
        f32x4 oacc[1];
        mm_stream<1, 16, 8, 0>(pkWout, w, lane, S, oacc);
        const float* bo = (w < 4) ? bmu : blv;
        int cl = ((w & 3) << 4) + li;
        float bv = bo[cl];
        float* ob = out + ((w < 4) ? 0 : 65536);
#pragma unroll
        for (int rg = 0; rg < 4; ++rg)
            ob[(long)(m0 + rb + rg) * 64 + cl] = oacc[0][rg] + bv;
    }
}

extern "C" void kernel_launch(void* const* d_in, const int* in_sizes, int n_in,
                              void* d_out, int out_size, void* d_ws, size_t ws_size,
                              hipStream_t stream)
{
    (void)in_sizes; (void)n_in; (void)out_size; (void)ws_size;
    const float* x   = (const float*)d_in[0];
    const float* t   = (const float*)d_in[1];
    const float* Wih = (const float*)d_in[2];
    const float* Whh = (const float*)d_in[3];
    const float* bih = (const float*)d_in[4];
    const float* bhh = (const float*)d_in[5];
    const float* W1  = (const float*)d_in[6];
    const float* b1  = (const float*)d_in[7];
    const float* W2  = (const float*)d_in[8];
    const float* b2  = (const float*)d_in[9];
    const float* Wmu = (const float*)d_in[10];
    const float* bmu = (const float*)d_in[11];
    const float* Wlv = (const float*)d_in[12];
    const float* blv = (const float*)d_in[13];
    float* out = (float*)d_out;

    char* wsb = (char*)d_ws;
    int8_t* pk8_1 = (int8_t*)wsb;                       // 256 KB
    int8_t* pk8_2 = (int8_t*)(wsb + 262144);            // 256 KB
    float*  sW1   = (float*)(wsb + 524288);             // 2 KB
    float*  sW2   = (float*)(wsb + 526336);             // 2 KB
    bf16* pkhh  = (bf16*)(wsb + (1l << 20));            // 3 MB   (2*1536*512)
    bf16* pkih  = pkhh + 1572864;                       // 0.75 MB (2*1536*128)
    bf16* pkout = pkih + 393216;                        // 0.25 MB (2*128*512)

    pack_i8<<<8, 64, 0, stream>>>(W1, pk8_1, sW1, 512, 512);
    pack_i8<<<8, 64, 0, stream>>>(W2, pk8_2, sW2, 512, 512);
    pack_split<<<3072, 256, 0, stream>>>(Whh, pkhh, 1536, 512, 96, 0);
    pack_split<<<768,  256, 0, stream>>>(Wih, pkih, 1536, 128, 96, 0);
    pack_split<<<128,  256, 0, stream>>>(Wmu, pkout, 64, 512, 8, 0);
    pack_split<<<128,  256, 0, stream>>>(Wlv, pkout, 64, 512, 8, 4);

    odegru_persist<<<64, 1024, 0, stream>>>(x, t, bih, bhh, b1, b2, bmu, blv,
                                            pk8_1, pk8_2, sW1, sW2,
                                            pkhh, pkih, pkout, out);
}